// Round 11
// baseline (1373.812 us; speedup 1.0000x reference)
//
#include <hip/hip_runtime.h>

// ---------------------------------------------------------------------------
// SPADE-style encoder.
// conv3: bf16 MFMA implicit-GEMM. R10: block re-tiled 8-wave -> 4-wave
//        (128px x 256co, wave tile 64x128 unchanged) so 2 blocks co-reside
//        per CU (R9 had 1 block/CU -> every barrier drain stalled the CU).
//        A-halo via async global_load_lds (XOR-swizzled src/read pair),
//        coalesced B tiles, lsum unioned with staging LDS.
// convT: bf16 MFMA per-parity-class GEMM with coalesced B tiles.
// conv0/conv1/conv2 + their instance-norms still fp32 vector.
// ---------------------------------------------------------------------------

#define B 8

typedef __attribute__((ext_vector_type(8))) short short8;
typedef __attribute__((ext_vector_type(4))) float f32x4;

static __device__ __forceinline__ unsigned short f2bf(float f) {
  union { float f; unsigned u; } v;
  v.f = f;
  unsigned r = v.u + 0x7fffu + ((v.u >> 16) & 1u);
  return (unsigned short)(r >> 16);
}
static __device__ __forceinline__ float bf2f(unsigned short h) {
  union { unsigned u; float f; } v;
  v.u = (unsigned)h << 16;
  return v.f;
}
static __device__ __forceinline__ float tanh_fast(float x) {
  float ax = fabsf(x);
  ax = fminf(ax, 20.f);
  const float e = __expf(-2.f * ax);
  const float t = (1.f - e) / (1.f + e);
  return __builtin_copysignf(t, x);
}

// async 16B global -> LDS (linear dest: wave-uniform base + lane*16)
static __device__ __forceinline__ void gload_lds16(const unsigned short* g,
                                                   unsigned short* l) {
  __builtin_amdgcn_global_load_lds(
      (const __attribute__((address_space(1))) unsigned int*)(const void*)g,
      (__attribute__((address_space(3))) unsigned int*)(void*)l, 16, 0, 0);
}

// ---------------- conv0: 3->32, reflect pad 1, 256x256 ----------------
__global__ __launch_bounds__(256) void conv0_kernel(
    const float* __restrict__ in, const float* __restrict__ w,
    const float* __restrict__ bias, float* __restrict__ out) {
  __shared__ float sw[32 * 27 + 32];
  for (int i = threadIdx.x; i < 32 * 27; i += 256) sw[i] = w[i];
  if (threadIdx.x < 32) sw[32 * 27 + threadIdx.x] = bias[threadIdx.x];
  __syncthreads();
  const int b = blockIdx.y;
  const int p = blockIdx.x * 256 + threadIdx.x;
  const int y = p >> 8, x = p & 255;
  const float* inb = in + (size_t)b * 3 * 65536;
  float v[27];
#pragma unroll
  for (int c = 0; c < 3; ++c) {
#pragma unroll
    for (int ky = 0; ky < 3; ++ky) {
      int iy = y + ky - 1;
      iy = iy < 0 ? -iy : (iy > 255 ? 510 - iy : iy);
#pragma unroll
      for (int kx = 0; kx < 3; ++kx) {
        int ix = x + kx - 1;
        ix = ix < 0 ? -ix : (ix > 255 ? 510 - ix : ix);
        v[c * 9 + ky * 3 + kx] = inb[c * 65536 + iy * 256 + ix];
      }
    }
  }
  float* ob = out + (size_t)b * 32 * 65536 + p;
#pragma unroll
  for (int co = 0; co < 32; ++co) {
    float a = sw[32 * 27 + co];
#pragma unroll
    for (int k = 0; k < 27; ++k) a = fmaf(v[k], sw[co * 27 + k], a);
    ob[(size_t)co * 65536] = a;
  }
}

// ---------------- fused instance-norm + leaky relu (in place, fp32) ----------
__global__ __launch_bounds__(256) void inorm_lrelu_kernel(float* __restrict__ x,
                                                          int HW) {
  const size_t base = (size_t)blockIdx.x * HW;
  float4* p = (float4*)(x + base);
  const int n4 = HW >> 2;
  float s = 0.f, q = 0.f;
  for (int i = threadIdx.x; i < n4; i += 256) {
    float4 v = p[i];
    s += (v.x + v.y) + (v.z + v.w);
    q += (v.x * v.x + v.y * v.y) + (v.z * v.z + v.w * v.w);
  }
  __shared__ float rs[256], rq[256];
  rs[threadIdx.x] = s;
  rq[threadIdx.x] = q;
  __syncthreads();
  for (int st = 128; st > 0; st >>= 1) {
    if (threadIdx.x < st) {
      rs[threadIdx.x] += rs[threadIdx.x + st];
      rq[threadIdx.x] += rq[threadIdx.x + st];
    }
    __syncthreads();
  }
  const float m = rs[0] / (float)HW;
  float var = rq[0] / (float)HW - m * m;
  var = var < 0.f ? 0.f : var;
  const float r = rsqrtf(var + 1e-5f);
  for (int i = threadIdx.x; i < n4; i += 256) {
    float4 v = p[i];
    v.x = (v.x - m) * r; v.x = v.x >= 0.f ? v.x : 0.2f * v.x;
    v.y = (v.y - m) * r; v.y = v.y >= 0.f ? v.y : 0.2f * v.y;
    v.z = (v.z - m) * r; v.z = v.z >= 0.f ? v.z : 0.2f * v.z;
    v.w = (v.w - m) * r; v.w = v.w >= 0.f ? v.w : 0.2f * v.w;
    p[i] = v;
  }
}

// ---------------- 3x3 stride-2 zero-pad-1 conv, 32 co per block ----------------
template <int CIN, int COUT, int HIN>
__global__ __launch_bounds__(256) void conv_s2_kernel(
    const float* __restrict__ in, const float* __restrict__ w,
    const float* __restrict__ bias, float* __restrict__ out) {
  constexpr int HOUT = HIN / 2;
  const int b = blockIdx.z;
  const int co0 = blockIdx.y * 32;
  const int p = blockIdx.x * 256 + threadIdx.x;
  const int oy = p / HOUT, ox = p % HOUT;
  float acc[32];
#pragma unroll
  for (int i = 0; i < 32; ++i) acc[i] = bias[co0 + i];
  const float* inb = in + (size_t)b * CIN * HIN * HIN;
  const int iy0 = 2 * oy - 1, ix0 = 2 * ox - 1;
  for (int ci = 0; ci < CIN; ++ci) {
    float v[9];
    const float* ip = inb + (size_t)ci * HIN * HIN;
#pragma unroll
    for (int ky = 0; ky < 3; ++ky) {
      const int iy = iy0 + ky;
      const bool yok = (unsigned)iy < (unsigned)HIN;
#pragma unroll
      for (int kx = 0; kx < 3; ++kx) {
        const int ix = ix0 + kx;
        const bool ok = yok && ((unsigned)ix < (unsigned)HIN);
        v[ky * 3 + kx] = ok ? ip[iy * HIN + ix] : 0.f;
      }
    }
    const float* wp = w + ((size_t)co0 * CIN + ci) * 9;
#pragma unroll
    for (int co = 0; co < 32; ++co) {
#pragma unroll
      for (int k = 0; k < 9; ++k)
        acc[co] = fmaf(v[k], wp[(size_t)co * CIN * 9 + k], acc[co]);
    }
  }
  float* ob = out + ((size_t)b * COUT + co0) * HOUT * HOUT + p;
#pragma unroll
  for (int co = 0; co < 32; ++co) ob[(size_t)co * HOUT * HOUT] = acc[co];
}

// -------- transpose x2: fp32 [b][128][4096] -> X2p bf16 [b][65][65][128] ----
__global__ __launch_bounds__(256) void transpose_x2_kernel(
    const float* __restrict__ x2, unsigned short* __restrict__ X2p) {
  const int b = blockIdx.y;
  const int p0 = (blockIdx.x & 63) * 64;
  const int ci0 = (blockIdx.x >> 6) * 64;
  __shared__ unsigned short T[64][66];
  const float* src = x2 + (size_t)b * 128 * 4096;
  const int t = threadIdx.x;
#pragma unroll
  for (int r = 0; r < 16; ++r) {
    const int ci_l = r * 4 + (t >> 6);
    const int p_l = t & 63;
    T[ci_l][p_l] = f2bf(src[(size_t)(ci0 + ci_l) * 4096 + p0 + p_l]);
  }
  __syncthreads();
  unsigned short* dst = X2p + (size_t)b * 65 * 65 * 128;
#pragma unroll
  for (int r = 0; r < 2; ++r) {
    const int p_l = r * 32 + (t >> 3);
    const int c0 = (t & 7) * 8;
    union { short8 v; unsigned short u[8]; } pk;
#pragma unroll
    for (int j = 0; j < 8; ++j) pk.u[j] = T[c0 + j][p_l];
    const int p = p0 + p_l;
    const int yy = p >> 6, xx = p & 63;
    *(short8*)(dst + ((size_t)yy * 65 + xx) * 128 + ci0 + c0) = pk.v;
  }
}

// ---------------- zero pad row 64 / col 64 of X2p ----------------
__global__ __launch_bounds__(256) void zpad_x2_kernel(unsigned short* __restrict__ X2p) {
  const int b = blockIdx.x;
  unsigned short* Xb = X2p + (size_t)b * 65 * 65 * 128;
  for (int i = threadIdx.x; i < 129 * 128; i += 256) {
    const int j = i >> 7, ci = i & 127;
    size_t off;
    if (j < 65) off = ((size_t)64 * 65 + j) * 128 + ci;
    else off = ((size_t)(j - 65) * 65 + 64) * 128 + ci;
    Xb[off] = 0;
  }
}

// -------- weight repack (coalesced tiles): wt fp32 [256][128][3][3] ->
// -------- Wtb2 bf16 [9][cot16][c4(4)][lane64][8] ----------------------------
__global__ __launch_bounds__(256) void wtprep_kernel(const float* __restrict__ wt,
                                                     unsigned short* __restrict__ Wtb2) {
  const int i = blockIdx.x * 256 + threadIdx.x;
  if (i >= 9 * 256 * 128) return;
  const int e = i & 7, lane = (i >> 3) & 63, c4 = (i >> 9) & 3;
  const int cot = (i >> 11) & 15, tap = i >> 15;
  const int co = cot * 16 + (lane & 15);
  const int ci = c4 * 32 + (lane >> 4) * 8 + e;
  Wtb2[i] = f2bf(wt[((size_t)co * 128 + ci) * 9 + tap]);
}

// ---------------- convT as bf16 MFMA per-parity-class GEMM ----------------
__global__ __launch_bounds__(256, 3) void convt_mfma_kernel(
    const unsigned short* __restrict__ X2p, const unsigned short* __restrict__ Wtb2,
    const float* __restrict__ bt, unsigned short* __restrict__ Y) {
  const int raw = blockIdx.x;
  const int swz = (raw & 7) * 256 + (raw >> 3);
  const int b = swz >> 8;
  const int rem = swz & 255;
  const int cls = rem >> 6;
  const int sy = rem & 63;
  const int py = cls & 1, px = cls >> 1;

  const int kyA = py ? 0 : 1, kxA = px ? 0 : 1;
  int tk[4], tdy[4], tdx[4];
  int ntaps = 0;
  tk[ntaps] = kyA * 3 + kxA; tdy[ntaps] = 0; tdx[ntaps] = 0; ++ntaps;
  if (px) { tk[ntaps] = kyA * 3 + 2; tdy[ntaps] = 0; tdx[ntaps] = 1; ++ntaps; }
  if (py) { tk[ntaps] = 6 + kxA; tdy[ntaps] = 1; tdx[ntaps] = 0; ++ntaps; }
  if (py && px) { tk[ntaps] = 8; tdy[ntaps] = 1; tdx[ntaps] = 1; ++ntaps; }

  constexpr int CS = 36;
  constexpr int BUFN = 2 * 65 * CS;
  __shared__ unsigned short As2[2 * BUFN];

  const int t = threadIdx.x;
  const int lane = t & 63;
  const int wn = t >> 6;
  const int lg = lane >> 4, lr = lane & 15;
  const int co_w = wn * 64;

  const unsigned short* Xb = X2p + (size_t)b * 65 * 65 * 128;

  int dof0, dof1, dof2;
  const unsigned short *sp0, *sp1, *sp2;
  bool sv2;
  {
    const int i0 = t, i1 = t + 256, i2 = t + 512;
    const int r0 = i0 / 260, c0_ = (i0 % 260) >> 2, h0 = i0 & 3;
    const int r1 = i1 / 260, c1_ = (i1 % 260) >> 2, h1 = i1 & 3;
    sv2 = i2 < 520;
    const int i2c = sv2 ? i2 : 512;
    const int r2 = i2c / 260, c2_ = (i2c % 260) >> 2, h2 = i2c & 3;
    dof0 = (r0 * 65 + c0_) * CS + h0 * 8;
    dof1 = (r1 * 65 + c1_) * CS + h1 * 8;
    dof2 = (r2 * 65 + c2_) * CS + h2 * 8;
    sp0 = Xb + ((size_t)(sy + r0) * 65 + c0_) * 128 + h0 * 8;
    sp1 = Xb + ((size_t)(sy + r1) * 65 + c1_) * 128 + h1 * 8;
    sp2 = Xb + ((size_t)(sy + r2) * 65 + c2_) * 128 + h2 * 8;
  }

  f32x4 acc[4][4];
#pragma unroll
  for (int mt = 0; mt < 4; ++mt)
#pragma unroll
    for (int nt = 0; nt < 4; ++nt) {
      f32x4 z = {0.f, 0.f, 0.f, 0.f};
      acc[mt][nt] = z;
    }

  {
    const short8 a = *(const short8*)sp0;
    const short8 bq = *(const short8*)sp1;
    short8 cq;
    if (sv2) cq = *(const short8*)sp2;
    *(short8*)(As2 + dof0) = a;
    *(short8*)(As2 + dof1) = bq;
    if (sv2) *(short8*)(As2 + dof2) = cq;
  }
  __syncthreads();

  const unsigned short* wlane = Wtb2 + (size_t)lane * 8;

  for (int c8 = 0; c8 < 4; ++c8) {
    short8 n0, n1, n2;
    if (c8 < 3) {
      const int cn = (c8 + 1) * 32;
      n0 = *(const short8*)(sp0 + cn);
      n1 = *(const short8*)(sp1 + cn);
      if (sv2) n2 = *(const short8*)(sp2 + cn);
    }
    const unsigned short* Ab = As2 + (c8 & 1) * BUFN;
    for (int tp = 0; tp < ntaps; ++tp) {
      const int dy = tdy[tp], dx = tdx[tp];
      short8 af[4];
#pragma unroll
      for (int mt = 0; mt < 4; ++mt)
        af[mt] = *(const short8*)(Ab + (dy * 65 + mt * 16 + lr + dx) * CS + lg * 8);
      const unsigned short* wt_ =
          wlane + (size_t)(((tk[tp] * 16 + wn * 4) * 4) + c8) * 512;
#pragma unroll
      for (int nt = 0; nt < 4; ++nt) {
        const short8 bf = *(const short8*)(wt_ + (size_t)nt * (4 * 512));
#pragma unroll
        for (int mt = 0; mt < 4; ++mt)
          acc[mt][nt] = __builtin_amdgcn_mfma_f32_16x16x32_bf16(
              af[mt], bf, acc[mt][nt], 0, 0, 0);
      }
    }
    if (c8 < 3) {
      unsigned short* Db = As2 + ((c8 + 1) & 1) * BUFN;
      *(short8*)(Db + dof0) = n0;
      *(short8*)(Db + dof1) = n1;
      if (sv2) *(short8*)(Db + dof2) = n2;
    }
    __syncthreads();
  }

  const int oy = 2 * sy + py;
  unsigned short* Yb = Y + ((size_t)b * 16384 + (size_t)oy * 128 + px) * 256;
  float bco[4];
#pragma unroll
  for (int nt = 0; nt < 4; ++nt) bco[nt] = bt[co_w + nt * 16 + lr];
#pragma unroll
  for (int mt = 0; mt < 4; ++mt) {
#pragma unroll
    for (int r = 0; r < 4; ++r) {
      const int sx = mt * 16 + lg * 4 + r;
      unsigned short* yp = Yb + (size_t)(2 * sx) * 256 + co_w + lr;
#pragma unroll
      for (int nt = 0; nt < 4; ++nt)
        yp[nt * 16] = f2bf(acc[mt][nt][r] + bco[nt]);
    }
  }
}

// ---------------- instance-norm stats over pixel-major Y ----------------
__global__ __launch_bounds__(256) void inorm_stats_kernel(
    const unsigned short* __restrict__ Y, float* __restrict__ ssum,
    float* __restrict__ ssq) {
  const int b = blockIdx.y, sl = blockIdx.x, c = threadIdx.x;
  const unsigned short* p = Y + ((size_t)b * 16384 + (size_t)sl * 1024) * 256 + c;
  float s = 0.f, q = 0.f;
  for (int i = 0; i < 1024; ++i) {
    const float v = bf2f(p[(size_t)i * 256]);
    s += v;
    q += v * v;
  }
  atomicAdd(&ssum[b * 256 + c], s);
  atomicAdd(&ssq[b * 256 + c], q);
}

// ------- apply IN + LReLU to Y, write bf16 into Xpad interior -------
__global__ __launch_bounds__(256) void inorm_apply_kernel(
    const unsigned short* __restrict__ Y, const float* __restrict__ ssum,
    const float* __restrict__ ssq, unsigned short* __restrict__ Xpad) {
  const int b = blockIdx.y, sl = blockIdx.x, c = threadIdx.x;
  const float m = ssum[b * 256 + c] * (1.f / 16384.f);
  float var = ssq[b * 256 + c] * (1.f / 16384.f) - m * m;
  var = var < 0.f ? 0.f : var;
  const float r = rsqrtf(var + 1e-5f);
  const unsigned short* p = Y + ((size_t)b * 16384 + (size_t)sl * 1024) * 256 + c;
  unsigned short* dst = Xpad + (size_t)b * 130 * 130 * 256 + c;
  for (int i = 0; i < 1024; ++i) {
    const int pix = sl * 1024 + i;
    const int yy = pix >> 7, xx = pix & 127;
    float v = bf2f(p[(size_t)i * 256]);
    v = (v - m) * r;
    v = v >= 0.f ? v : 0.2f * v;
    dst[((size_t)(yy + 1) * 130 + (xx + 1)) * 256] = f2bf(v);
  }
}

// ---------------- reflect borders of Xpad: rows then cols ----------------
__global__ __launch_bounds__(256) void pad_rows_kernel(unsigned short* __restrict__ Xp) {
  const int b = blockIdx.x >> 1, side = blockIdx.x & 1;
  unsigned short* Xb = Xp + (size_t)b * 130 * 130 * 256;
  const int dr = side ? 129 : 0, sr = side ? 127 : 2;
  for (int i = threadIdx.x; i < 4096; i += 256) {
    const int c = 1 + (i >> 5), o = (i & 31) * 8;
    *(short8*)(Xb + ((size_t)dr * 130 + c) * 256 + o) =
        *(const short8*)(Xb + ((size_t)sr * 130 + c) * 256 + o);
  }
}
__global__ __launch_bounds__(256) void pad_cols_kernel(unsigned short* __restrict__ Xp) {
  const int b = blockIdx.x >> 1, side = blockIdx.x & 1;
  unsigned short* Xb = Xp + (size_t)b * 130 * 130 * 256;
  const int dc = side ? 129 : 0, sc = side ? 127 : 2;
  for (int i = threadIdx.x; i < 130 * 32; i += 256) {
    const int r = i >> 5, o = (i & 31) * 8;
    *(short8*)(Xb + ((size_t)r * 130 + dc) * 256 + o) =
        *(const short8*)(Xb + ((size_t)r * 130 + sc) * 256 + o);
  }
}

// ------ weight repack (coalesced tiles): w3 fp32 [512][256][9] ->
// ------ Wb2 bf16 [9][cot32][c8(8)][lane64][8]; co=cot*16+lr, ci=c8*32+lg*8+e
__global__ __launch_bounds__(256) void wprep_kernel(const float* __restrict__ w3,
                                                    unsigned short* __restrict__ Wb2) {
  const int i = blockIdx.x * 256 + threadIdx.x;
  if (i >= 9 * 512 * 256) return;
  const int e = i & 7, lane = (i >> 3) & 63, c8 = (i >> 9) & 7;
  const int cot = (i >> 12) & 31, tap = i >> 17;
  const int co = cot * 16 + (lane & 15);
  const int ci = c8 * 32 + (lane >> 4) * 8 + e;
  Wb2[i] = f2bf(w3[((size_t)co * 256 + ci) * 9 + tap]);
}

// ---------------- label extraction + counts from one-hot segmap ----------------
__global__ __launch_bounds__(256) void label_kernel(
    const float* __restrict__ segmap, int* __restrict__ labels,
    float* __restrict__ cnt) {
  const int b = blockIdx.y;
  const int p = blockIdx.x * 256 + threadIdx.x;
  const int i = p >> 7, j = p & 127;
  const float* sp = segmap + (size_t)b * 19 * 65536 + (2 * i) * 256 + 2 * j;
  int lab = 0;
#pragma unroll
  for (int s = 0; s < 19; ++s)
    if (sp[(size_t)s * 65536] != 0.f) lab = s;
  labels[b * 16384 + p] = lab;
  atomicAdd(&cnt[b * 19 + lab], 1.0f);
}

// ---------------- conv3: bf16 MFMA implicit GEMM + tanh + region pool --------
// R10: Block = 256 threads (4 waves) = one image row (128 px) x 256 co.
// Wave grid 2Mx2N, wave tile 64px x 128co, acc 4x8 f32x4 = 128 regs/wave.
// 228 regs/wave -> 2 waves/SIMD -> TWO blocks co-resident per CU: one
// block's barrier drain overlaps the other's MFMA stream (R9 had 1 block).
// A-halo async global_load_lds, XOR-swizzle pair: slot (E,hs) holds global
// ci-quarter hs ^ ((E>>1)&3); reads apply the same involution.
__global__ __launch_bounds__(256, 2) void conv3_mfma_pool_kernel(
    const unsigned short* __restrict__ Xpad, const unsigned short* __restrict__ Wb2,
    const float* __restrict__ bias, const int* __restrict__ labels,
    float* __restrict__ sums) {
  // XCD swizzle: 2048 = 8 XCDs x 256 -> one batch per XCD
  const int raw = blockIdx.x;
  const int swz = (raw & 7) * 256 + (raw >> 3);
  const int b = swz >> 8;
  const int rem = swz & 255;
  const int y = rem >> 1;
  const int coh = rem & 1;

  constexpr int SLOTS = 1600;  // 1560 used (3*130*4) + tail pad
  __shared__ unsigned short Asw[2 * SLOTS * 8];  // 51.2 KB
  float* lsum = (float*)Asw;                     // epilogue reuse (19.4 KB)

  const int t = threadIdx.x;
  const int lane = t & 63;
  const int wave = t >> 6;     // 0..3
  const int wm = wave >> 1;    // 0..1: M group (64 px)
  const int wn = wave & 1;     // 0..1: N group (128 co)
  const int lg = lane >> 4, lr = lane & 15;
  const int co_w = coh * 256 + wn * 128;

  const unsigned short* Xb = Xpad + (size_t)b * 130 * 130 * 256;

  // per-thread global sources: slots t+k*256 (k=0..5) + tail (wave0, lane<24)
  // slot s = E*4 + hs (E = r*130+c); stored quarter h = hs ^ ((E>>1)&3)
  const unsigned short* sp[7];
  {
#pragma unroll
    for (int k = 0; k < 7; ++k) {
      int s;
      if (k < 6) s = t + k * 256;
      else s = (t < 24) ? (1536 + t) : 1536;
      const int r = s / 520, rm = s % 520, c = rm >> 2, hs = rm & 3;
      const int E = r * 130 + c;
      const int h = hs ^ ((E >> 1) & 3);
      sp[k] = Xb + ((size_t)(y + r) * 130 + c) * 256 + h * 8;
    }
  }

  f32x4 acc[4][8];
#pragma unroll
  for (int mt = 0; mt < 4; ++mt)
#pragma unroll
    for (int nt = 0; nt < 8; ++nt) {
      f32x4 z = {0.f, 0.f, 0.f, 0.f};
      acc[mt][nt] = z;
    }

  const unsigned short* wlane = Wb2 + (size_t)lane * 8;

  // async stage of one 32-ci chunk into buffer `bufSel` (ci offset `off`)
  const int wslot = wave * 64;
#define STAGE(bufSel, off)                                                   \
  {                                                                          \
    unsigned short* base_ = Asw + (bufSel) * (SLOTS * 8);                    \
    gload_lds16(sp[0] + (off), base_ + (size_t)wslot * 8);                   \
    gload_lds16(sp[1] + (off), base_ + (size_t)(wslot + 256) * 8);           \
    gload_lds16(sp[2] + (off), base_ + (size_t)(wslot + 512) * 8);           \
    gload_lds16(sp[3] + (off), base_ + (size_t)(wslot + 768) * 8);           \
    gload_lds16(sp[4] + (off), base_ + (size_t)(wslot + 1024) * 8);          \
    gload_lds16(sp[5] + (off), base_ + (size_t)(wslot + 1280) * 8);          \
    if (wave == 0 && lane < 24)                                              \
      gload_lds16(sp[6] + (off), base_ + (size_t)1536 * 8);                  \
  }

  STAGE(0, 0)
  __syncthreads();

  for (int c8 = 0; c8 < 8; ++c8) {
    if (c8 < 7) STAGE((c8 + 1) & 1, (c8 + 1) * 32)
    const unsigned short* Ab = Asw + (c8 & 1) * (SLOTS * 8);
#pragma unroll
    for (int ky = 0; ky < 3; ++ky) {
#pragma unroll
      for (int kx = 0; kx < 3; ++kx) {
        const unsigned short* wt_ =
            wlane +
            (size_t)(((ky * 3 + kx) * 32 + coh * 16 + wn * 8) * 8 + c8) * 512;
        short8 bfv[8];
#pragma unroll
        for (int nt = 0; nt < 8; ++nt)
          bfv[nt] = *(const short8*)(wt_ + (size_t)nt * (8 * 512));
        short8 af[4];
#pragma unroll
        for (int mt = 0; mt < 4; ++mt) {
          const int E = ky * 130 + wm * 64 + mt * 16 + lr + kx;
          const int hh = lg ^ ((E >> 1) & 3);
          af[mt] = *(const short8*)(Ab + (size_t)E * 32 + hh * 8);
        }
#pragma unroll
        for (int nt = 0; nt < 8; ++nt) {
#pragma unroll
          for (int mt = 0; mt < 4; ++mt)
            acc[mt][nt] = __builtin_amdgcn_mfma_f32_16x16x32_bf16(
                af[mt], bfv[nt], acc[mt][nt], 0, 0, 0);
        }
      }
    }
    __syncthreads();
  }
#undef STAGE

  // epilogue: staging LDS dead -> zero lsum in same space
  for (int i = t; i < 19 * 256; i += 256) lsum[i] = 0.f;
  __syncthreads();

  const int* labp = labels + b * 16384 + y * 128;
  float bco[8];
#pragma unroll
  for (int nt = 0; nt < 8; ++nt) bco[nt] = bias[co_w + nt * 16 + lr];
#pragma unroll
  for (int mt = 0; mt < 4; ++mt) {
#pragma unroll
    for (int r = 0; r < 4; ++r) {
      const int lab = labp[wm * 64 + mt * 16 + lg * 4 + r];
#pragma unroll
      for (int nt = 0; nt < 8; ++nt) {
        const float v = tanh_fast(acc[mt][nt][r] + bco[nt]);
        atomicAdd(&lsum[lab * 256 + wn * 128 + nt * 16 + lr], v);
      }
    }
  }
  __syncthreads();
  for (int i = t; i < 19 * 256; i += 256) {
    const float v = lsum[i];
    if (v != 0.f) {
      const int sI = i >> 8, c = i & 255;
      atomicAdd(&sums[((size_t)b * 19 + sI) * 512 + coh * 256 + c], v);
    }
  }
}

// ---------------- finalize: out = cnt>0 ? sums/max(cnt,1) : 0 ----------------
__global__ __launch_bounds__(256) void finalize_kernel(
    const float* __restrict__ sums, const float* __restrict__ cnt,
    float* __restrict__ out) {
  const int i = blockIdx.x * 256 + threadIdx.x;
  if (i >= B * 19 * 512) return;
  const int bs = i >> 9;
  const float c = cnt[bs];
  out[i] = c > 0.f ? sums[i] / fmaxf(c, 1.f) : 0.f;
}

// ---------------------------------------------------------------------------
extern "C" void kernel_launch(void* const* d_in, const int* in_sizes, int n_in,
                              void* d_out, int out_size, void* d_ws,
                              size_t ws_size, hipStream_t stream) {
  const float* input = (const float*)d_in[0];
  const float* segmap = (const float*)d_in[1];
  const float* w0 = (const float*)d_in[2];
  const float* b0 = (const float*)d_in[3];
  const float* w1 = (const float*)d_in[4];
  const float* b1 = (const float*)d_in[5];
  const float* w2 = (const float*)d_in[6];
  const float* b2 = (const float*)d_in[7];
  const float* wt = (const float*)d_in[8];
  const float* bt = (const float*)d_in[9];
  const float* w3 = (const float*)d_in[10];
  const float* b3 = (const float*)d_in[11];
  float* out = (float*)d_out;

  float* ws = (float*)d_ws;
  float* x0 = ws;                                    // 16,777,216 f
  float* x1 = x0 + 16777216;                         //  8,388,608 f
  float* x2 = x1 + 8388608;                          //  4,194,304 f
  unsigned short* X2p = (unsigned short*)(x2 + 4194304);  // 4,326,400 us
  unsigned short* Y = X2p + 4326400;                 // 33,554,432 us
  float* sums = (float*)(Y + 33554432);              //     77,824 f
  float* cnt = sums + 77824;                         //        152 f
  float* ssum = cnt + 152;                           //      2,048 f
  float* ssq = ssum + 2048;                          //      2,048 f
  int* labels = (int*)(ssq + 2048);                  //    131,072 i
  unsigned short* Wb2 = (unsigned short*)(labels + 131072);  // 1,179,648 us
  unsigned short* Wtb2 = Wb2 + 1179648;              //    294,912 us
  unsigned short* Xpad = (unsigned short*)ws;        // 69.2MB over x0+x1 (dead)

  hipMemsetAsync(sums, 0, (77824 + 152 + 2048 + 2048) * sizeof(float), stream);

  wprep_kernel<<<dim3((9 * 512 * 256 + 255) / 256), 256, 0, stream>>>(w3, Wb2);
  wtprep_kernel<<<dim3((9 * 256 * 128 + 255) / 256), 256, 0, stream>>>(wt, Wtb2);
  conv0_kernel<<<dim3(256, B), 256, 0, stream>>>(input, w0, b0, x0);
  inorm_lrelu_kernel<<<dim3(B * 32), 256, 0, stream>>>(x0, 65536);
  conv_s2_kernel<32, 64, 256><<<dim3(64, 2, B), 256, 0, stream>>>(x0, w1, b1, x1);
  inorm_lrelu_kernel<<<dim3(B * 64), 256, 0, stream>>>(x1, 16384);
  conv_s2_kernel<64, 128, 128><<<dim3(16, 4, B), 256, 0, stream>>>(x1, w2, b2, x2);
  inorm_lrelu_kernel<<<dim3(B * 128), 256, 0, stream>>>(x2, 4096);
  transpose_x2_kernel<<<dim3(128, B), 256, 0, stream>>>(x2, X2p);
  zpad_x2_kernel<<<dim3(B), 256, 0, stream>>>(X2p);
  convt_mfma_kernel<<<dim3(2048), 256, 0, stream>>>(X2p, Wtb2, bt, Y);
  inorm_stats_kernel<<<dim3(16, B), 256, 0, stream>>>(Y, ssum, ssq);
  inorm_apply_kernel<<<dim3(16, B), 256, 0, stream>>>(Y, ssum, ssq, Xpad);
  pad_rows_kernel<<<dim3(2 * B), 256, 0, stream>>>(Xpad);
  pad_cols_kernel<<<dim3(2 * B), 256, 0, stream>>>(Xpad);
  label_kernel<<<dim3(64, B), 256, 0, stream>>>(segmap, labels, cnt);
  conv3_mfma_pool_kernel<<<dim3(2048), 256, 0, stream>>>(Xpad, Wb2, b3, labels, sums);
  finalize_kernel<<<dim3((B * 19 * 512 + 255) / 256), 256, 0, stream>>>(sums, cnt, out);
}

// Round 12
// 1159.598 us; speedup vs baseline: 1.1847x; 1.1847x over previous
//
#include <hip/hip_runtime.h>

// ---------------------------------------------------------------------------
// SPADE-style encoder.
// conv3: bf16 MFMA implicit-GEMM. R11: re-tiled per m97 evidence — block =
//        4 waves = 128px x 128co, wave tile 64x64 (acc 64 regs) ->
//        ~160 regs/wave -> 3 waves/SIMD, 3 blocks/CU (12 waves/CU mixed
//        phases hide latency; R6-R10's 64x128 wave tile pinned 2 waves/SIMD).
//        A-halo via async global_load_lds (XOR src/read pair), coalesced B.
// inorm_stats/apply: short8-vectorized, 512-block grids, LDS-reduced stats.
// convT: bf16 MFMA per-parity-class GEMM with coalesced B tiles.
// conv0/conv1/conv2 + their instance-norms still fp32 vector.
// ---------------------------------------------------------------------------

#define B 8

typedef __attribute__((ext_vector_type(8))) short short8;
typedef __attribute__((ext_vector_type(4))) float f32x4;

static __device__ __forceinline__ unsigned short f2bf(float f) {
  union { float f; unsigned u; } v;
  v.f = f;
  unsigned r = v.u + 0x7fffu + ((v.u >> 16) & 1u);
  return (unsigned short)(r >> 16);
}
static __device__ __forceinline__ float bf2f(unsigned short h) {
  union { unsigned u; float f; } v;
  v.u = (unsigned)h << 16;
  return v.f;
}
static __device__ __forceinline__ float tanh_fast(float x) {
  float ax = fabsf(x);
  ax = fminf(ax, 20.f);
  const float e = __expf(-2.f * ax);
  const float t = (1.f - e) / (1.f + e);
  return __builtin_copysignf(t, x);
}

// async 16B global -> LDS (linear dest: wave-uniform base + lane*16)
static __device__ __forceinline__ void gload_lds16(const unsigned short* g,
                                                   unsigned short* l) {
  __builtin_amdgcn_global_load_lds(
      (const __attribute__((address_space(1))) unsigned int*)(const void*)g,
      (__attribute__((address_space(3))) unsigned int*)(void*)l, 16, 0, 0);
}

// ---------------- conv0: 3->32, reflect pad 1, 256x256 ----------------
__global__ __launch_bounds__(256) void conv0_kernel(
    const float* __restrict__ in, const float* __restrict__ w,
    const float* __restrict__ bias, float* __restrict__ out) {
  __shared__ float sw[32 * 27 + 32];
  for (int i = threadIdx.x; i < 32 * 27; i += 256) sw[i] = w[i];
  if (threadIdx.x < 32) sw[32 * 27 + threadIdx.x] = bias[threadIdx.x];
  __syncthreads();
  const int b = blockIdx.y;
  const int p = blockIdx.x * 256 + threadIdx.x;
  const int y = p >> 8, x = p & 255;
  const float* inb = in + (size_t)b * 3 * 65536;
  float v[27];
#pragma unroll
  for (int c = 0; c < 3; ++c) {
#pragma unroll
    for (int ky = 0; ky < 3; ++ky) {
      int iy = y + ky - 1;
      iy = iy < 0 ? -iy : (iy > 255 ? 510 - iy : iy);
#pragma unroll
      for (int kx = 0; kx < 3; ++kx) {
        int ix = x + kx - 1;
        ix = ix < 0 ? -ix : (ix > 255 ? 510 - ix : ix);
        v[c * 9 + ky * 3 + kx] = inb[c * 65536 + iy * 256 + ix];
      }
    }
  }
  float* ob = out + (size_t)b * 32 * 65536 + p;
#pragma unroll
  for (int co = 0; co < 32; ++co) {
    float a = sw[32 * 27 + co];
#pragma unroll
    for (int k = 0; k < 27; ++k) a = fmaf(v[k], sw[co * 27 + k], a);
    ob[(size_t)co * 65536] = a;
  }
}

// ---------------- fused instance-norm + leaky relu (in place, fp32) ----------
__global__ __launch_bounds__(256) void inorm_lrelu_kernel(float* __restrict__ x,
                                                          int HW) {
  const size_t base = (size_t)blockIdx.x * HW;
  float4* p = (float4*)(x + base);
  const int n4 = HW >> 2;
  float s = 0.f, q = 0.f;
  for (int i = threadIdx.x; i < n4; i += 256) {
    float4 v = p[i];
    s += (v.x + v.y) + (v.z + v.w);
    q += (v.x * v.x + v.y * v.y) + (v.z * v.z + v.w * v.w);
  }
  __shared__ float rs[256], rq[256];
  rs[threadIdx.x] = s;
  rq[threadIdx.x] = q;
  __syncthreads();
  for (int st = 128; st > 0; st >>= 1) {
    if (threadIdx.x < st) {
      rs[threadIdx.x] += rs[threadIdx.x + st];
      rq[threadIdx.x] += rq[threadIdx.x + st];
    }
    __syncthreads();
  }
  const float m = rs[0] / (float)HW;
  float var = rq[0] / (float)HW - m * m;
  var = var < 0.f ? 0.f : var;
  const float r = rsqrtf(var + 1e-5f);
  for (int i = threadIdx.x; i < n4; i += 256) {
    float4 v = p[i];
    v.x = (v.x - m) * r; v.x = v.x >= 0.f ? v.x : 0.2f * v.x;
    v.y = (v.y - m) * r; v.y = v.y >= 0.f ? v.y : 0.2f * v.y;
    v.z = (v.z - m) * r; v.z = v.z >= 0.f ? v.z : 0.2f * v.z;
    v.w = (v.w - m) * r; v.w = v.w >= 0.f ? v.w : 0.2f * v.w;
    p[i] = v;
  }
}

// ---------------- 3x3 stride-2 zero-pad-1 conv, 32 co per block ----------------
template <int CIN, int COUT, int HIN>
__global__ __launch_bounds__(256) void conv_s2_kernel(
    const float* __restrict__ in, const float* __restrict__ w,
    const float* __restrict__ bias, float* __restrict__ out) {
  constexpr int HOUT = HIN / 2;
  const int b = blockIdx.z;
  const int co0 = blockIdx.y * 32;
  const int p = blockIdx.x * 256 + threadIdx.x;
  const int oy = p / HOUT, ox = p % HOUT;
  float acc[32];
#pragma unroll
  for (int i = 0; i < 32; ++i) acc[i] = bias[co0 + i];
  const float* inb = in + (size_t)b * CIN * HIN * HIN;
  const int iy0 = 2 * oy - 1, ix0 = 2 * ox - 1;
  for (int ci = 0; ci < CIN; ++ci) {
    float v[9];
    const float* ip = inb + (size_t)ci * HIN * HIN;
#pragma unroll
    for (int ky = 0; ky < 3; ++ky) {
      const int iy = iy0 + ky;
      const bool yok = (unsigned)iy < (unsigned)HIN;
#pragma unroll
      for (int kx = 0; kx < 3; ++kx) {
        const int ix = ix0 + kx;
        const bool ok = yok && ((unsigned)ix < (unsigned)HIN);
        v[ky * 3 + kx] = ok ? ip[iy * HIN + ix] : 0.f;
      }
    }
    const float* wp = w + ((size_t)co0 * CIN + ci) * 9;
#pragma unroll
    for (int co = 0; co < 32; ++co) {
#pragma unroll
      for (int k = 0; k < 9; ++k)
        acc[co] = fmaf(v[k], wp[(size_t)co * CIN * 9 + k], acc[co]);
    }
  }
  float* ob = out + ((size_t)b * COUT + co0) * HOUT * HOUT + p;
#pragma unroll
  for (int co = 0; co < 32; ++co) ob[(size_t)co * HOUT * HOUT] = acc[co];
}

// -------- transpose x2: fp32 [b][128][4096] -> X2p bf16 [b][65][65][128] ----
__global__ __launch_bounds__(256) void transpose_x2_kernel(
    const float* __restrict__ x2, unsigned short* __restrict__ X2p) {
  const int b = blockIdx.y;
  const int p0 = (blockIdx.x & 63) * 64;
  const int ci0 = (blockIdx.x >> 6) * 64;
  __shared__ unsigned short T[64][66];
  const float* src = x2 + (size_t)b * 128 * 4096;
  const int t = threadIdx.x;
#pragma unroll
  for (int r = 0; r < 16; ++r) {
    const int ci_l = r * 4 + (t >> 6);
    const int p_l = t & 63;
    T[ci_l][p_l] = f2bf(src[(size_t)(ci0 + ci_l) * 4096 + p0 + p_l]);
  }
  __syncthreads();
  unsigned short* dst = X2p + (size_t)b * 65 * 65 * 128;
#pragma unroll
  for (int r = 0; r < 2; ++r) {
    const int p_l = r * 32 + (t >> 3);
    const int c0 = (t & 7) * 8;
    union { short8 v; unsigned short u[8]; } pk;
#pragma unroll
    for (int j = 0; j < 8; ++j) pk.u[j] = T[c0 + j][p_l];
    const int p = p0 + p_l;
    const int yy = p >> 6, xx = p & 63;
    *(short8*)(dst + ((size_t)yy * 65 + xx) * 128 + ci0 + c0) = pk.v;
  }
}

// ---------------- zero pad row 64 / col 64 of X2p ----------------
__global__ __launch_bounds__(256) void zpad_x2_kernel(unsigned short* __restrict__ X2p) {
  const int b = blockIdx.x;
  unsigned short* Xb = X2p + (size_t)b * 65 * 65 * 128;
  for (int i = threadIdx.x; i < 129 * 128; i += 256) {
    const int j = i >> 7, ci = i & 127;
    size_t off;
    if (j < 65) off = ((size_t)64 * 65 + j) * 128 + ci;
    else off = ((size_t)(j - 65) * 65 + 64) * 128 + ci;
    Xb[off] = 0;
  }
}

// -------- weight repack (coalesced tiles): wt fp32 [256][128][3][3] ->
// -------- Wtb2 bf16 [9][cot16][c4(4)][lane64][8] ----------------------------
__global__ __launch_bounds__(256) void wtprep_kernel(const float* __restrict__ wt,
                                                     unsigned short* __restrict__ Wtb2) {
  const int i = blockIdx.x * 256 + threadIdx.x;
  if (i >= 9 * 256 * 128) return;
  const int e = i & 7, lane = (i >> 3) & 63, c4 = (i >> 9) & 3;
  const int cot = (i >> 11) & 15, tap = i >> 15;
  const int co = cot * 16 + (lane & 15);
  const int ci = c4 * 32 + (lane >> 4) * 8 + e;
  Wtb2[i] = f2bf(wt[((size_t)co * 128 + ci) * 9 + tap]);
}

// ---------------- convT as bf16 MFMA per-parity-class GEMM ----------------
__global__ __launch_bounds__(256, 3) void convt_mfma_kernel(
    const unsigned short* __restrict__ X2p, const unsigned short* __restrict__ Wtb2,
    const float* __restrict__ bt, unsigned short* __restrict__ Y) {
  const int raw = blockIdx.x;
  const int swz = (raw & 7) * 256 + (raw >> 3);
  const int b = swz >> 8;
  const int rem = swz & 255;
  const int cls = rem >> 6;
  const int sy = rem & 63;
  const int py = cls & 1, px = cls >> 1;

  const int kyA = py ? 0 : 1, kxA = px ? 0 : 1;
  int tk[4], tdy[4], tdx[4];
  int ntaps = 0;
  tk[ntaps] = kyA * 3 + kxA; tdy[ntaps] = 0; tdx[ntaps] = 0; ++ntaps;
  if (px) { tk[ntaps] = kyA * 3 + 2; tdy[ntaps] = 0; tdx[ntaps] = 1; ++ntaps; }
  if (py) { tk[ntaps] = 6 + kxA; tdy[ntaps] = 1; tdx[ntaps] = 0; ++ntaps; }
  if (py && px) { tk[ntaps] = 8; tdy[ntaps] = 1; tdx[ntaps] = 1; ++ntaps; }

  constexpr int CS = 36;
  constexpr int BUFN = 2 * 65 * CS;
  __shared__ unsigned short As2[2 * BUFN];

  const int t = threadIdx.x;
  const int lane = t & 63;
  const int wn = t >> 6;
  const int lg = lane >> 4, lr = lane & 15;
  const int co_w = wn * 64;

  const unsigned short* Xb = X2p + (size_t)b * 65 * 65 * 128;

  int dof0, dof1, dof2;
  const unsigned short *sp0, *sp1, *sp2;
  bool sv2;
  {
    const int i0 = t, i1 = t + 256, i2 = t + 512;
    const int r0 = i0 / 260, c0_ = (i0 % 260) >> 2, h0 = i0 & 3;
    const int r1 = i1 / 260, c1_ = (i1 % 260) >> 2, h1 = i1 & 3;
    sv2 = i2 < 520;
    const int i2c = sv2 ? i2 : 512;
    const int r2 = i2c / 260, c2_ = (i2c % 260) >> 2, h2 = i2c & 3;
    dof0 = (r0 * 65 + c0_) * CS + h0 * 8;
    dof1 = (r1 * 65 + c1_) * CS + h1 * 8;
    dof2 = (r2 * 65 + c2_) * CS + h2 * 8;
    sp0 = Xb + ((size_t)(sy + r0) * 65 + c0_) * 128 + h0 * 8;
    sp1 = Xb + ((size_t)(sy + r1) * 65 + c1_) * 128 + h1 * 8;
    sp2 = Xb + ((size_t)(sy + r2) * 65 + c2_) * 128 + h2 * 8;
  }

  f32x4 acc[4][4];
#pragma unroll
  for (int mt = 0; mt < 4; ++mt)
#pragma unroll
    for (int nt = 0; nt < 4; ++nt) {
      f32x4 z = {0.f, 0.f, 0.f, 0.f};
      acc[mt][nt] = z;
    }

  {
    const short8 a = *(const short8*)sp0;
    const short8 bq = *(const short8*)sp1;
    short8 cq;
    if (sv2) cq = *(const short8*)sp2;
    *(short8*)(As2 + dof0) = a;
    *(short8*)(As2 + dof1) = bq;
    if (sv2) *(short8*)(As2 + dof2) = cq;
  }
  __syncthreads();

  const unsigned short* wlane = Wtb2 + (size_t)lane * 8;

  for (int c8 = 0; c8 < 4; ++c8) {
    short8 n0, n1, n2;
    if (c8 < 3) {
      const int cn = (c8 + 1) * 32;
      n0 = *(const short8*)(sp0 + cn);
      n1 = *(const short8*)(sp1 + cn);
      if (sv2) n2 = *(const short8*)(sp2 + cn);
    }
    const unsigned short* Ab = As2 + (c8 & 1) * BUFN;
    for (int tp = 0; tp < ntaps; ++tp) {
      const int dy = tdy[tp], dx = tdx[tp];
      short8 af[4];
#pragma unroll
      for (int mt = 0; mt < 4; ++mt)
        af[mt] = *(const short8*)(Ab + (dy * 65 + mt * 16 + lr + dx) * CS + lg * 8);
      const unsigned short* wt_ =
          wlane + (size_t)(((tk[tp] * 16 + wn * 4) * 4) + c8) * 512;
#pragma unroll
      for (int nt = 0; nt < 4; ++nt) {
        const short8 bf = *(const short8*)(wt_ + (size_t)nt * (4 * 512));
#pragma unroll
        for (int mt = 0; mt < 4; ++mt)
          acc[mt][nt] = __builtin_amdgcn_mfma_f32_16x16x32_bf16(
              af[mt], bf, acc[mt][nt], 0, 0, 0);
      }
    }
    if (c8 < 3) {
      unsigned short* Db = As2 + ((c8 + 1) & 1) * BUFN;
      *(short8*)(Db + dof0) = n0;
      *(short8*)(Db + dof1) = n1;
      if (sv2) *(short8*)(Db + dof2) = n2;
    }
    __syncthreads();
  }

  const int oy = 2 * sy + py;
  unsigned short* Yb = Y + ((size_t)b * 16384 + (size_t)oy * 128 + px) * 256;
  float bco[4];
#pragma unroll
  for (int nt = 0; nt < 4; ++nt) bco[nt] = bt[co_w + nt * 16 + lr];
#pragma unroll
  for (int mt = 0; mt < 4; ++mt) {
#pragma unroll
    for (int r = 0; r < 4; ++r) {
      const int sx = mt * 16 + lg * 4 + r;
      unsigned short* yp = Yb + (size_t)(2 * sx) * 256 + co_w + lr;
#pragma unroll
      for (int nt = 0; nt < 4; ++nt)
        yp[nt * 16] = f2bf(acc[mt][nt][r] + bco[nt]);
    }
  }
}

// ------- instance-norm stats over pixel-major Y (short8, LDS-reduced) -------
// grid (64, B): 64 slices of 256 rows. thread t: row-group t>>5, ch c0=(t&31)*8
__global__ __launch_bounds__(256) void inorm_stats_kernel(
    const unsigned short* __restrict__ Y, float* __restrict__ ssum,
    float* __restrict__ ssq) {
  const int b = blockIdx.y, sl = blockIdx.x;
  const int t = threadIdx.x;
  const int rg = t >> 5;
  const int c0 = (t & 31) * 8;
  const unsigned short* base = Y + ((size_t)b * 16384 + sl * 256) * 256;
  float s[8], q[8];
#pragma unroll
  for (int j = 0; j < 8; ++j) { s[j] = 0.f; q[j] = 0.f; }
  for (int i = 0; i < 32; ++i) {
    union { short8 v; unsigned short u[8]; } pk;
    pk.v = *(const short8*)(base + (size_t)(rg + i * 8) * 256 + c0);
#pragma unroll
    for (int j = 0; j < 8; ++j) {
      const float v = bf2f(pk.u[j]);
      s[j] += v;
      q[j] += v * v;
    }
  }
  __shared__ float sm[2][8][256];
#pragma unroll
  for (int j = 0; j < 8; ++j) {
    sm[0][rg][c0 + j] = s[j];
    sm[1][rg][c0 + j] = q[j];
  }
  __syncthreads();
  float ts = 0.f, tq = 0.f;
#pragma unroll
  for (int g = 0; g < 8; ++g) {
    ts += sm[0][g][t];
    tq += sm[1][g][t];
  }
  atomicAdd(&ssum[b * 256 + t], ts);
  atomicAdd(&ssq[b * 256 + t], tq);
}

// ------- apply IN + LReLU to Y (short8), write bf16 into Xpad interior -------
__global__ __launch_bounds__(256) void inorm_apply_kernel(
    const unsigned short* __restrict__ Y, const float* __restrict__ ssum,
    const float* __restrict__ ssq, unsigned short* __restrict__ Xpad) {
  const int b = blockIdx.y, sl = blockIdx.x;
  const int t = threadIdx.x;
  const int rg = t >> 5;
  const int c0 = (t & 31) * 8;
  float m[8], r[8];
#pragma unroll
  for (int j = 0; j < 8; ++j) {
    const float mm = ssum[b * 256 + c0 + j] * (1.f / 16384.f);
    float var = ssq[b * 256 + c0 + j] * (1.f / 16384.f) - mm * mm;
    var = var < 0.f ? 0.f : var;
    m[j] = mm;
    r[j] = rsqrtf(var + 1e-5f);
  }
  const unsigned short* base = Y + ((size_t)b * 16384 + sl * 256) * 256;
  unsigned short* dstb = Xpad + (size_t)b * 130 * 130 * 256;
  for (int i = 0; i < 32; ++i) {
    const int row = sl * 256 + rg + i * 8;
    const int yy = row >> 7, xx = row & 127;
    union { short8 v; unsigned short u[8]; } pk;
    pk.v = *(const short8*)(base + (size_t)(rg + i * 8) * 256 + c0);
#pragma unroll
    for (int j = 0; j < 8; ++j) {
      float v = bf2f(pk.u[j]);
      v = (v - m[j]) * r[j];
      v = v >= 0.f ? v : 0.2f * v;
      pk.u[j] = f2bf(v);
    }
    *(short8*)(dstb + ((size_t)(yy + 1) * 130 + (xx + 1)) * 256 + c0) = pk.v;
  }
}

// ---------------- reflect borders of Xpad: rows then cols ----------------
__global__ __launch_bounds__(256) void pad_rows_kernel(unsigned short* __restrict__ Xp) {
  const int b = blockIdx.x >> 1, side = blockIdx.x & 1;
  unsigned short* Xb = Xp + (size_t)b * 130 * 130 * 256;
  const int dr = side ? 129 : 0, sr = side ? 127 : 2;
  for (int i = threadIdx.x; i < 4096; i += 256) {
    const int c = 1 + (i >> 5), o = (i & 31) * 8;
    *(short8*)(Xb + ((size_t)dr * 130 + c) * 256 + o) =
        *(const short8*)(Xb + ((size_t)sr * 130 + c) * 256 + o);
  }
}
__global__ __launch_bounds__(256) void pad_cols_kernel(unsigned short* __restrict__ Xp) {
  const int b = blockIdx.x >> 1, side = blockIdx.x & 1;
  unsigned short* Xb = Xp + (size_t)b * 130 * 130 * 256;
  const int dc = side ? 129 : 0, sc = side ? 127 : 2;
  for (int i = threadIdx.x; i < 130 * 32; i += 256) {
    const int r = i >> 5, o = (i & 31) * 8;
    *(short8*)(Xb + ((size_t)r * 130 + dc) * 256 + o) =
        *(const short8*)(Xb + ((size_t)r * 130 + sc) * 256 + o);
  }
}

// ------ weight repack (coalesced tiles): w3 fp32 [512][256][9] ->
// ------ Wb2 bf16 [9][cot32][c8(8)][lane64][8]; co=cot*16+lr, ci=c8*32+lg*8+e
__global__ __launch_bounds__(256) void wprep_kernel(const float* __restrict__ w3,
                                                    unsigned short* __restrict__ Wb2) {
  const int i = blockIdx.x * 256 + threadIdx.x;
  if (i >= 9 * 512 * 256) return;
  const int e = i & 7, lane = (i >> 3) & 63, c8 = (i >> 9) & 7;
  const int cot = (i >> 12) & 31, tap = i >> 17;
  const int co = cot * 16 + (lane & 15);
  const int ci = c8 * 32 + (lane >> 4) * 8 + e;
  Wb2[i] = f2bf(w3[((size_t)co * 256 + ci) * 9 + tap]);
}

// ---------------- label extraction + counts from one-hot segmap ----------------
__global__ __launch_bounds__(256) void label_kernel(
    const float* __restrict__ segmap, int* __restrict__ labels,
    float* __restrict__ cnt) {
  const int b = blockIdx.y;
  const int p = blockIdx.x * 256 + threadIdx.x;
  const int i = p >> 7, j = p & 127;
  const float* sp = segmap + (size_t)b * 19 * 65536 + (2 * i) * 256 + 2 * j;
  int lab = 0;
#pragma unroll
  for (int s = 0; s < 19; ++s)
    if (sp[(size_t)s * 65536] != 0.f) lab = s;
  labels[b * 16384 + p] = lab;
  atomicAdd(&cnt[b * 19 + lab], 1.0f);
}

// ---------------- conv3: bf16 MFMA implicit GEMM + tanh + region pool --------
// R11: Block = 256 threads (4 waves) = one image row (128 px) x 128 co.
// Wave grid 2Mx2N, wave tile 64px x 64co, acc 4x4 f32x4 = 64 regs/wave ->
// ~160 regs -> 3 waves/SIMD, 3 blocks/CU (LDS 51.2KB x3 = 153.6 <= 160KB).
// A-halo async global_load_lds with XOR src/read pair; coalesced Wb2 tiles.
__global__ __launch_bounds__(256, 3) void conv3_mfma_pool_kernel(
    const unsigned short* __restrict__ Xpad, const unsigned short* __restrict__ Wb2,
    const float* __restrict__ bias, const int* __restrict__ labels,
    float* __restrict__ sums) {
  // XCD swizzle: 4096 = 8 XCDs x 512 -> one batch per XCD
  const int raw = blockIdx.x;
  const int swz = (raw & 7) * 512 + (raw >> 3);
  const int b = swz >> 9;
  const int rem = swz & 511;
  const int y = rem >> 2;   // image row
  const int coq = rem & 3;  // co quarter (128 co)

  constexpr int SLOTS = 1600;  // 1560 used (3*130*4) + tail pad
  __shared__ unsigned short Asw[2 * SLOTS * 8];  // 51.2 KB
  float* lsum = (float*)Asw;                     // epilogue reuse (9.7 KB)

  const int t = threadIdx.x;
  const int lane = t & 63;
  const int wave = t >> 6;     // 0..3
  const int wm = wave >> 1;    // 0..1: M group (64 px)
  const int wn = wave & 1;     // 0..1: N group (64 co)
  const int lg = lane >> 4, lr = lane & 15;
  const int co_w = coq * 128 + wn * 64;

  const unsigned short* Xb = Xpad + (size_t)b * 130 * 130 * 256;

  // per-thread global sources: slots t+k*256 (k=0..5) + tail (wave0, lane<24)
  // slot s = E*4 + hs (E = r*130+c); stored quarter h = hs ^ ((E>>1)&3)
  const unsigned short* sp[7];
  {
#pragma unroll
    for (int k = 0; k < 7; ++k) {
      int s;
      if (k < 6) s = t + k * 256;
      else s = (t < 24) ? (1536 + t) : 1536;
      const int r = s / 520, rm = s % 520, c = rm >> 2, hs = rm & 3;
      const int E = r * 130 + c;
      const int h = hs ^ ((E >> 1) & 3);
      sp[k] = Xb + ((size_t)(y + r) * 130 + c) * 256 + h * 8;
    }
  }

  f32x4 acc[4][4];
#pragma unroll
  for (int mt = 0; mt < 4; ++mt)
#pragma unroll
    for (int nt = 0; nt < 4; ++nt) {
      f32x4 z = {0.f, 0.f, 0.f, 0.f};
      acc[mt][nt] = z;
    }

  const unsigned short* wlane = Wb2 + (size_t)lane * 8;

  const int wslot = wave * 64;
#define STAGE(bufSel, off)                                                   \
  {                                                                          \
    unsigned short* base_ = Asw + (bufSel) * (SLOTS * 8);                    \
    gload_lds16(sp[0] + (off), base_ + (size_t)wslot * 8);                   \
    gload_lds16(sp[1] + (off), base_ + (size_t)(wslot + 256) * 8);           \
    gload_lds16(sp[2] + (off), base_ + (size_t)(wslot + 512) * 8);           \
    gload_lds16(sp[3] + (off), base_ + (size_t)(wslot + 768) * 8);           \
    gload_lds16(sp[4] + (off), base_ + (size_t)(wslot + 1024) * 8);          \
    gload_lds16(sp[5] + (off), base_ + (size_t)(wslot + 1280) * 8);          \
    if (wave == 0 && lane < 24)                                              \
      gload_lds16(sp[6] + (off), base_ + (size_t)1536 * 8);                  \
  }

  STAGE(0, 0)
  __syncthreads();

  for (int c8 = 0; c8 < 8; ++c8) {
    if (c8 < 7) STAGE((c8 + 1) & 1, (c8 + 1) * 32)
    const unsigned short* Ab = Asw + (c8 & 1) * (SLOTS * 8);
#pragma unroll
    for (int ky = 0; ky < 3; ++ky) {
#pragma unroll
      for (int kx = 0; kx < 3; ++kx) {
        const unsigned short* wt_ =
            wlane +
            (size_t)(((ky * 3 + kx) * 32 + coq * 8 + wn * 4) * 8 + c8) * 512;
        short8 bfv[4];
#pragma unroll
        for (int nt = 0; nt < 4; ++nt)
          bfv[nt] = *(const short8*)(wt_ + (size_t)nt * (8 * 512));
        short8 af[4];
#pragma unroll
        for (int mt = 0; mt < 4; ++mt) {
          const int E = ky * 130 + wm * 64 + mt * 16 + lr + kx;
          const int hh = lg ^ ((E >> 1) & 3);
          af[mt] = *(const short8*)(Ab + (size_t)E * 32 + hh * 8);
        }
#pragma unroll
        for (int nt = 0; nt < 4; ++nt) {
#pragma unroll
          for (int mt = 0; mt < 4; ++mt)
            acc[mt][nt] = __builtin_amdgcn_mfma_f32_16x16x32_bf16(
                af[mt], bfv[nt], acc[mt][nt], 0, 0, 0);
        }
      }
    }
    __syncthreads();
  }
#undef STAGE

  // epilogue: staging LDS dead -> zero lsum in same space
  for (int i = t; i < 19 * 128; i += 256) lsum[i] = 0.f;
  __syncthreads();

  const int* labp = labels + b * 16384 + y * 128;
  float bco[4];
#pragma unroll
  for (int nt = 0; nt < 4; ++nt) bco[nt] = bias[co_w + nt * 16 + lr];
#pragma unroll
  for (int mt = 0; mt < 4; ++mt) {
#pragma unroll
    for (int r = 0; r < 4; ++r) {
      const int lab = labp[wm * 64 + mt * 16 + lg * 4 + r];
#pragma unroll
      for (int nt = 0; nt < 4; ++nt) {
        const float v = tanh_fast(acc[mt][nt][r] + bco[nt]);
        atomicAdd(&lsum[lab * 128 + wn * 64 + nt * 16 + lr], v);
      }
    }
  }
  __syncthreads();
  for (int i = t; i < 19 * 128; i += 256) {
    const float v = lsum[i];
    if (v != 0.f) {
      const int sI = i >> 7, c = i & 127;
      atomicAdd(&sums[((size_t)b * 19 + sI) * 512 + coq * 128 + c], v);
    }
  }
}

// ---------------- finalize: out = cnt>0 ? sums/max(cnt,1) : 0 ----------------
__global__ __launch_bounds__(256) void finalize_kernel(
    const float* __restrict__ sums, const float* __restrict__ cnt,
    float* __restrict__ out) {
  const int i = blockIdx.x * 256 + threadIdx.x;
  if (i >= B * 19 * 512) return;
  const int bs = i >> 9;
  const float c = cnt[bs];
  out[i] = c > 0.f ? sums[i] / fmaxf(c, 1.f) : 0.f;
}

// ---------------------------------------------------------------------------
extern "C" void kernel_launch(void* const* d_in, const int* in_sizes, int n_in,
                              void* d_out, int out_size, void* d_ws,
                              size_t ws_size, hipStream_t stream) {
  const float* input = (const float*)d_in[0];
  const float* segmap = (const float*)d_in[1];
  const float* w0 = (const float*)d_in[2];
  const float* b0 = (const float*)d_in[3];
  const float* w1 = (const float*)d_in[4];
  const float* b1 = (const float*)d_in[5];
  const float* w2 = (const float*)d_in[6];
  const float* b2 = (const float*)d_in[7];
  const float* wt = (const float*)d_in[8];
  const float* bt = (const float*)d_in[9];
  const float* w3 = (const float*)d_in[10];
  const float* b3 = (const float*)d_in[11];
  float* out = (float*)d_out;

  float* ws = (float*)d_ws;
  float* x0 = ws;                                    // 16,777,216 f
  float* x1 = x0 + 16777216;                         //  8,388,608 f
  float* x2 = x1 + 8388608;                          //  4,194,304 f
  unsigned short* X2p = (unsigned short*)(x2 + 4194304);  // 4,326,400 us
  unsigned short* Y = X2p + 4326400;                 // 33,554,432 us
  float* sums = (float*)(Y + 33554432);              //     77,824 f
  float* cnt = sums + 77824;                         //        152 f
  float* ssum = cnt + 152;                           //      2,048 f
  float* ssq = ssum + 2048;                          //      2,048 f
  int* labels = (int*)(ssq + 2048);                  //    131,072 i
  unsigned short* Wb2 = (unsigned short*)(labels + 131072);  // 1,179,648 us
  unsigned short* Wtb2 = Wb2 + 1179648;              //    294,912 us
  unsigned short* Xpad = (unsigned short*)ws;        // 69.2MB over x0+x1 (dead)

  hipMemsetAsync(sums, 0, (77824 + 152 + 2048 + 2048) * sizeof(float), stream);

  wprep_kernel<<<dim3((9 * 512 * 256 + 255) / 256), 256, 0, stream>>>(w3, Wb2);
  wtprep_kernel<<<dim3((9 * 256 * 128 + 255) / 256), 256, 0, stream>>>(wt, Wtb2);
  conv0_kernel<<<dim3(256, B), 256, 0, stream>>>(input, w0, b0, x0);
  inorm_lrelu_kernel<<<dim3(B * 32), 256, 0, stream>>>(x0, 65536);
  conv_s2_kernel<32, 64, 256><<<dim3(64, 2, B), 256, 0, stream>>>(x0, w1, b1, x1);
  inorm_lrelu_kernel<<<dim3(B * 64), 256, 0, stream>>>(x1, 16384);
  conv_s2_kernel<64, 128, 128><<<dim3(16, 4, B), 256, 0, stream>>>(x1, w2, b2, x2);
  inorm_lrelu_kernel<<<dim3(B * 128), 256, 0, stream>>>(x2, 4096);
  transpose_x2_kernel<<<dim3(128, B), 256, 0, stream>>>(x2, X2p);
  zpad_x2_kernel<<<dim3(B), 256, 0, stream>>>(X2p);
  convt_mfma_kernel<<<dim3(2048), 256, 0, stream>>>(X2p, Wtb2, bt, Y);
  inorm_stats_kernel<<<dim3(64, B), 256, 0, stream>>>(Y, ssum, ssq);
  inorm_apply_kernel<<<dim3(64, B), 256, 0, stream>>>(Y, ssum, ssq, Xpad);
  pad_rows_kernel<<<dim3(2 * B), 256, 0, stream>>>(Xpad);
  pad_cols_kernel<<<dim3(2 * B), 256, 0, stream>>>(Xpad);
  label_kernel<<<dim3(64, B), 256, 0, stream>>>(segmap, labels, cnt);
  conv3_mfma_pool_kernel<<<dim3(4096), 256, 0, stream>>>(Xpad, Wb2, b3, labels, sums);
  finalize_kernel<<<dim3((B * 19 * 512 + 255) / 256), 256, 0, stream>>>(sums, cnt, out);
}